// Round 2
// baseline (427.416 us; speedup 1.0000x reference)
//
#include <hip/hip_runtime.h>
#include <hip/hip_bf16.h>

#define N_NODES 100000
#define N_EDGES 1600000
#define D_NODE 96
#define D_EDGE 32
#define N_GRAPHS 128
#define BN_EPS 1e-5f

#define EDGE_BLOCKS 1024
#define EDGE_THREADS 256

static __device__ __forceinline__ unsigned short f2bf(float f) {
    __hip_bfloat16 h = __float2bfloat16(f);
    return *reinterpret_cast<unsigned short*>(&h);
}
static __device__ __forceinline__ void unpack_bf16x2(unsigned u, float& lo, float& hi) {
    lo = __uint_as_float(u << 16);
    hi = __uint_as_float(u & 0xFFFF0000u);
}

// ---------------- prep: fold BN into weights (one thread per element) ----------------
// ws floats: w1n[16*96] | w1e[16*32] | cw[33]  (cw: 0..15=C, 16..31=W2, 32=b2)
__global__ __launch_bounds__(256) void prep_kernel(
    const float* __restrict__ W1, const float* __restrict__ b1,
    const float* __restrict__ gamma, const float* __restrict__ beta,
    const float* __restrict__ rmean, const float* __restrict__ rvar,
    const float* __restrict__ W2, const float* __restrict__ b2,
    float* __restrict__ w1n, float* __restrict__ w1e, float* __restrict__ cw) {
    int idx = blockIdx.x * 256 + threadIdx.x;
    if (idx < 1536) {                       // w1n[k][j], k=idx/96, j=idx%96
        int k = idx / 96, j = idx % 96;
        float A = gamma[k] * rsqrtf(rvar[k] + BN_EPS);
        w1n[idx] = A * W1[k * (D_NODE + D_EDGE) + j];
    } else if (idx < 2048) {                // w1e[k][j], k=(idx-1536)/32, j=%32
        int r = idx - 1536;
        int k = r / 32, j = r % 32;
        float A = gamma[k] * rsqrtf(rvar[k] + BN_EPS);
        w1e[r] = A * W1[k * (D_NODE + D_EDGE) + D_NODE + j];
    } else if (idx < 2064) {                // cw[0..15]
        int k = idx - 2048;
        float A = gamma[k] * rsqrtf(rvar[k] + BN_EPS);
        cw[k] = A * (b1[k] - rmean[k]) + beta[k];
    } else if (idx < 2080) {                // cw[16..31] = W2
        int k = idx - 2064;
        cw[16 + k] = W2[k];
    } else if (idx == 2080) {
        cw[32] = b2[0];
    }
}

// ---------------- node projection: y[n][k] = sum_j x[n][j]*w1n[k][j], bf16 out ----------------
__global__ __launch_bounds__(256) void node_proj_kernel(const float* __restrict__ x,
                                                        const float* __restrict__ w1n,
                                                        unsigned short* __restrict__ y) {
    __shared__ __align__(16) float sw[16 * 96];
    for (int i = threadIdx.x; i < 16 * 96; i += 256) sw[i] = w1n[i];
    __syncthreads();

    int n = blockIdx.x * 256 + threadIdx.x;
    if (n >= N_NODES) return;

    const float4* xr = (const float4*)(x + (size_t)n * D_NODE);
    float acc[16];
#pragma unroll
    for (int k = 0; k < 16; ++k) acc[k] = 0.f;
#pragma unroll
    for (int j4 = 0; j4 < D_NODE / 4; ++j4) {
        float4 xv = xr[j4];
#pragma unroll
        for (int k = 0; k < 16; ++k) {
            float4 w = *(const float4*)&sw[k * 96 + j4 * 4];  // uniform addr -> LDS broadcast
            acc[k] = fmaf(xv.x, w.x, acc[k]);
            acc[k] = fmaf(xv.y, w.y, acc[k]);
            acc[k] = fmaf(xv.z, w.z, acc[k]);
            acc[k] = fmaf(xv.w, w.w, acc[k]);
        }
    }
    // pack 16 bf16 -> 32B
    unsigned w[8];
#pragma unroll
    for (int i = 0; i < 8; ++i)
        w[i] = (unsigned)f2bf(acc[2 * i]) | ((unsigned)f2bf(acc[2 * i + 1]) << 16);
    uint4* yr = (uint4*)(y + (size_t)n * 16);
    yr[0] = make_uint4(w[0], w[1], w[2], w[3]);
    yr[1] = make_uint4(w[4], w[5], w[6], w[7]);
}

// ---------------- edge kernel: msg per edge -> per-graph LDS bins -> per-block partials ----------------
__global__ __launch_bounds__(EDGE_THREADS) void edge_kernel(
    const float* __restrict__ ea, const int* __restrict__ eidx,
    const int* __restrict__ batch, const unsigned short* __restrict__ y,
    const float* __restrict__ w1e, const float* __restrict__ cw,
    float* __restrict__ partials) {
    __shared__ __align__(16) float sw[16 * 32];
    __shared__ float scw[33];
    __shared__ float bins[N_GRAPHS];
    int t = threadIdx.x;
    for (int i = t; i < 16 * 32; i += EDGE_THREADS) sw[i] = w1e[i];
    if (t < 33) scw[t] = cw[t];
    if (t < N_GRAPHS) bins[t] = 0.f;
    __syncthreads();

    const int* srcp = eidx;
    const int* dstp = eidx + N_EDGES;

    for (int e = blockIdx.x * EDGE_THREADS + t; e < N_EDGES; e += EDGE_BLOCKS * EDGE_THREADS) {
        int s = srcp[e];
        int d = dstp[e];

        const float4* er = (const float4*)(ea + (size_t)e * D_EDGE);
        float4 ev[8];
#pragma unroll
        for (int i = 0; i < 8; ++i) ev[i] = er[i];

        // gather y row (16 bf16 = 32B)
        const uint4* yrow = (const uint4*)(y + (size_t)s * 16);
        uint4 y0 = yrow[0], y1 = yrow[1];
        float ya[16];
        unpack_bf16x2(y0.x, ya[0], ya[1]);
        unpack_bf16x2(y0.y, ya[2], ya[3]);
        unpack_bf16x2(y0.z, ya[4], ya[5]);
        unpack_bf16x2(y0.w, ya[6], ya[7]);
        unpack_bf16x2(y1.x, ya[8], ya[9]);
        unpack_bf16x2(y1.y, ya[10], ya[11]);
        unpack_bf16x2(y1.z, ya[12], ya[13]);
        unpack_bf16x2(y1.w, ya[14], ya[15]);

        float msg = scw[32];
#pragma unroll
        for (int k = 0; k < 16; ++k) {
            const float4* wr = (const float4*)&sw[k * 32];  // uniform addr -> LDS broadcast
            float z = 0.f;
#pragma unroll
            for (int i = 0; i < 8; ++i) {
                float4 w = wr[i];
                z = fmaf(ev[i].x, w.x, z);
                z = fmaf(ev[i].y, w.y, z);
                z = fmaf(ev[i].z, w.z, z);
                z = fmaf(ev[i].w, w.w, z);
            }
            float h = z + ya[k] + scw[k];
            msg = fmaf(fmaxf(h, 0.f), scw[16 + k], msg);
        }

        int g = batch[d];
        atomicAdd(&bins[g], msg);
    }

    __syncthreads();
    if (t < N_GRAPHS) partials[(size_t)blockIdx.x * N_GRAPHS + t] = bins[t];
}

// ---------------- final reduce: out[g] = sum_b partials[b][g] ----------------
__global__ __launch_bounds__(256) void reduce_kernel(const float* __restrict__ partials,
                                                     float* __restrict__ out) {
    __shared__ float s[256];
    int g = blockIdx.x;
    float acc = 0.f;
    for (int b = threadIdx.x; b < EDGE_BLOCKS; b += 256)
        acc += partials[(size_t)b * N_GRAPHS + g];
    s[threadIdx.x] = acc;
    __syncthreads();
    for (int w = 128; w > 0; w >>= 1) {
        if (threadIdx.x < w) s[threadIdx.x] += s[threadIdx.x + w];
        __syncthreads();
    }
    if (threadIdx.x == 0) out[g] = s[0];
}

extern "C" void kernel_launch(void* const* d_in, const int* in_sizes, int n_in,
                              void* d_out, int out_size, void* d_ws, size_t ws_size,
                              hipStream_t stream) {
    const float* x     = (const float*)d_in[0];
    const float* ea    = (const float*)d_in[1];
    const int*   eidx  = (const int*)d_in[2];
    const int*   batch = (const int*)d_in[3];
    const float* W1    = (const float*)d_in[4];
    const float* b1    = (const float*)d_in[5];
    const float* gamma = (const float*)d_in[6];
    const float* beta  = (const float*)d_in[7];
    const float* rmean = (const float*)d_in[8];
    const float* rvar  = (const float*)d_in[9];
    const float* W2    = (const float*)d_in[10];
    const float* b2    = (const float*)d_in[11];
    float* out = (float*)d_out;

    float* ws = (float*)d_ws;
    // ws layout (float units):
    float*          w1n      = ws;            // 1536
    float*          w1e      = ws + 1536;     // 512
    float*          cw       = ws + 2048;     // 33, pad to 4096
    unsigned short* y        = (unsigned short*)(ws + 4096);           // N_NODES*16 bf16 = 800000 floats
    float*          partials = ws + 4096 + 800000;                     // EDGE_BLOCKS*128

    prep_kernel<<<9, 256, 0, stream>>>(W1, b1, gamma, beta, rmean, rvar, W2, b2, w1n, w1e, cw);
    node_proj_kernel<<<(N_NODES + 255) / 256, 256, 0, stream>>>(x, w1n, y);
    edge_kernel<<<EDGE_BLOCKS, EDGE_THREADS, 0, stream>>>(ea, eidx, batch, y, w1e, cw, partials);
    reduce_kernel<<<N_GRAPHS, 256, 0, stream>>>(partials, out);
}

// Round 4
// 417.712 us; speedup vs baseline: 1.0232x; 1.0232x over previous
//
#include <hip/hip_runtime.h>
#include <hip/hip_bf16.h>

#define N_NODES 100000
#define N_EDGES 1600000
#define D_NODE 96
#define D_EDGE 32
#define N_GRAPHS 128
#define BN_EPS 1e-5f

#define EDGE_BLOCKS 1024
#define EDGE_THREADS 256
#define EDGE_STRIDE (EDGE_BLOCKS * EDGE_THREADS)

typedef float vfloat4 __attribute__((ext_vector_type(4)));   // clang-native: ok for nontemporal builtins
typedef unsigned vuint4 __attribute__((ext_vector_type(4)));

static __device__ __forceinline__ unsigned short f2bf(float f) {
    __hip_bfloat16 h = __float2bfloat16(f);
    return *reinterpret_cast<unsigned short*>(&h);
}
static __device__ __forceinline__ void unpack_bf16x2(unsigned u, float& lo, float& hi) {
    lo = __uint_as_float(u << 16);
    hi = __uint_as_float(u & 0xFFFF0000u);
}

// ---------------- prep: fold BN into weights (one thread per element) ----------------
// ws floats: w1n[16*96] | w1e[16*32] | cw[33]  (cw: 0..15=C, 16..31=W2, 32=b2)
__global__ __launch_bounds__(256) void prep_kernel(
    const float* __restrict__ W1, const float* __restrict__ b1,
    const float* __restrict__ gamma, const float* __restrict__ beta,
    const float* __restrict__ rmean, const float* __restrict__ rvar,
    const float* __restrict__ W2, const float* __restrict__ b2,
    float* __restrict__ w1n, float* __restrict__ w1e, float* __restrict__ cw) {
    int idx = blockIdx.x * 256 + threadIdx.x;
    if (idx < 1536) {                       // w1n[k][j]
        int k = idx / 96, j = idx % 96;
        float A = gamma[k] * rsqrtf(rvar[k] + BN_EPS);
        w1n[idx] = A * W1[k * (D_NODE + D_EDGE) + j];
    } else if (idx < 2048) {                // w1e[k][j]
        int r = idx - 1536;
        int k = r / 32, j = r % 32;
        float A = gamma[k] * rsqrtf(rvar[k] + BN_EPS);
        w1e[r] = A * W1[k * (D_NODE + D_EDGE) + D_NODE + j];
    } else if (idx < 2064) {                // cw[0..15] = C
        int k = idx - 2048;
        float A = gamma[k] * rsqrtf(rvar[k] + BN_EPS);
        cw[k] = A * (b1[k] - rmean[k]) + beta[k];
    } else if (idx < 2080) {                // cw[16..31] = W2
        int k = idx - 2064;
        cw[16 + k] = W2[k];
    } else if (idx == 2080) {
        cw[32] = b2[0];
    }
}

// ---------------- node projection: y[n][k] = C[k] + sum_j x[n][j]*w1n[k][j], bf16 out ----
// Weights read via wave-uniform global addresses -> compiler emits s_load (SMEM pipe).
__global__ __launch_bounds__(256) void node_proj_kernel(const float* __restrict__ x,
                                                        const float* __restrict__ w1n,
                                                        const float* __restrict__ cw,
                                                        unsigned short* __restrict__ y) {
    int n = blockIdx.x * 256 + threadIdx.x;
    if (n >= N_NODES) return;

    const vfloat4* xr = (const vfloat4*)(x + (size_t)n * D_NODE);
    float acc[16];
#pragma unroll
    for (int k = 0; k < 16; ++k) acc[k] = cw[k];   // fold BN constant into y
#pragma unroll
    for (int j4 = 0; j4 < D_NODE / 4; ++j4) {
        vfloat4 xv = xr[j4];
#pragma unroll
        for (int k = 0; k < 16; ++k) {
            const float* w = w1n + k * D_NODE + j4 * 4;  // uniform -> s_load
            acc[k] = fmaf(xv.x, w[0], acc[k]);
            acc[k] = fmaf(xv.y, w[1], acc[k]);
            acc[k] = fmaf(xv.z, w[2], acc[k]);
            acc[k] = fmaf(xv.w, w[3], acc[k]);
        }
    }
    unsigned p[8];
#pragma unroll
    for (int i = 0; i < 8; ++i)
        p[i] = (unsigned)f2bf(acc[2 * i]) | ((unsigned)f2bf(acc[2 * i + 1]) << 16);
    vuint4* yr = (vuint4*)(y + (size_t)n * 16);
    yr[0] = vuint4{p[0], p[1], p[2], p[3]};
    yr[1] = vuint4{p[4], p[5], p[6], p[7]};
}

// ---------------- edge kernel: software-pipelined gathers, s_load weights ----------------
__global__ __launch_bounds__(EDGE_THREADS, 3) void edge_kernel(
    const float* __restrict__ ea, const int* __restrict__ eidx,
    const int* __restrict__ batch, const unsigned short* __restrict__ y,
    const float* __restrict__ w1e, const float* __restrict__ cw,
    float* __restrict__ partials) {
    __shared__ float bins[N_GRAPHS];
    int t = threadIdx.x;
    if (t < N_GRAPHS) bins[t] = 0.f;
    __syncthreads();

    const int* srcp = eidx;
    const int* dstp = eidx + N_EDGES;

    int e = blockIdx.x * EDGE_THREADS + t;

    // prefetch registers (iteration n+1's data)
    vfloat4 nev[8];
    vuint4 ny0, ny1;
    int ng = 0;
    bool valid = e < N_EDGES;
    if (valid) {
        int s = srcp[e], d = dstp[e];
        const vfloat4* er = (const vfloat4*)(ea + (size_t)e * D_EDGE);
#pragma unroll
        for (int i = 0; i < 8; ++i) nev[i] = __builtin_nontemporal_load(er + i);
        const vuint4* yr = (const vuint4*)(y + (size_t)s * 16);
        ny0 = yr[0];
        ny1 = yr[1];
        ng = batch[d];
    }

    while (valid) {
        // retire prefetched data into current regs (this is where vmcnt waits land)
        vfloat4 ev[8];
#pragma unroll
        for (int i = 0; i < 8; ++i) ev[i] = nev[i];
        vuint4 y0 = ny0, y1 = ny1;
        int g = ng;

        // issue next iteration's loads BEFORE the 512-FMA chain (latency hidden)
        int e2 = e + EDGE_STRIDE;
        valid = e2 < N_EDGES;
        if (valid) {
            int s = srcp[e2], d = dstp[e2];
            const vfloat4* er = (const vfloat4*)(ea + (size_t)e2 * D_EDGE);
#pragma unroll
            for (int i = 0; i < 8; ++i) nev[i] = __builtin_nontemporal_load(er + i);
            const vuint4* yr = (const vuint4*)(y + (size_t)s * 16);
            ny0 = yr[0];
            ny1 = yr[1];
            ng = batch[d];
        }
        e = e2;

        float ya[16];
        unpack_bf16x2(y0.x, ya[0], ya[1]);
        unpack_bf16x2(y0.y, ya[2], ya[3]);
        unpack_bf16x2(y0.z, ya[4], ya[5]);
        unpack_bf16x2(y0.w, ya[6], ya[7]);
        unpack_bf16x2(y1.x, ya[8], ya[9]);
        unpack_bf16x2(y1.y, ya[10], ya[11]);
        unpack_bf16x2(y1.z, ya[12], ya[13]);
        unpack_bf16x2(y1.w, ya[14], ya[15]);

        float msg = cw[32];
#pragma unroll
        for (int k = 0; k < 16; ++k) {
            const float* wr = w1e + k * D_EDGE;   // uniform -> s_load
            float z = 0.f;
#pragma unroll
            for (int i = 0; i < 8; ++i) {
                z = fmaf(ev[i].x, wr[i * 4 + 0], z);
                z = fmaf(ev[i].y, wr[i * 4 + 1], z);
                z = fmaf(ev[i].z, wr[i * 4 + 2], z);
                z = fmaf(ev[i].w, wr[i * 4 + 3], z);
            }
            float h = z + ya[k];                  // C already folded into y
            msg = fmaf(fmaxf(h, 0.f), cw[16 + k], msg);
        }

        atomicAdd(&bins[g], msg);
    }

    __syncthreads();
    if (t < N_GRAPHS) partials[(size_t)blockIdx.x * N_GRAPHS + t] = bins[t];
}

// ---------------- final reduce: out[g] = sum_b partials[b][g] ----------------
__global__ __launch_bounds__(256) void reduce_kernel(const float* __restrict__ partials,
                                                     float* __restrict__ out) {
    __shared__ float s[256];
    int g = blockIdx.x;
    float acc = 0.f;
    for (int b = threadIdx.x; b < EDGE_BLOCKS; b += 256)
        acc += partials[(size_t)b * N_GRAPHS + g];
    s[threadIdx.x] = acc;
    __syncthreads();
    for (int w = 128; w > 0; w >>= 1) {
        if (threadIdx.x < w) s[threadIdx.x] += s[threadIdx.x + w];
        __syncthreads();
    }
    if (threadIdx.x == 0) out[g] = s[0];
}

extern "C" void kernel_launch(void* const* d_in, const int* in_sizes, int n_in,
                              void* d_out, int out_size, void* d_ws, size_t ws_size,
                              hipStream_t stream) {
    const float* x     = (const float*)d_in[0];
    const float* ea    = (const float*)d_in[1];
    const int*   eidx  = (const int*)d_in[2];
    const int*   batch = (const int*)d_in[3];
    const float* W1    = (const float*)d_in[4];
    const float* b1    = (const float*)d_in[5];
    const float* gamma = (const float*)d_in[6];
    const float* beta  = (const float*)d_in[7];
    const float* rmean = (const float*)d_in[8];
    const float* rvar  = (const float*)d_in[9];
    const float* W2    = (const float*)d_in[10];
    const float* b2    = (const float*)d_in[11];
    float* out = (float*)d_out;

    float* ws = (float*)d_ws;
    // ws layout (float units):
    float*          w1n      = ws;            // 1536
    float*          w1e      = ws + 1536;     // 512
    float*          cw       = ws + 2048;     // 33, pad to 4096
    unsigned short* y        = (unsigned short*)(ws + 4096);   // N_NODES*16 bf16
    float*          partials = ws + 4096 + 800000;             // EDGE_BLOCKS*128

    prep_kernel<<<9, 256, 0, stream>>>(W1, b1, gamma, beta, rmean, rvar, W2, b2, w1n, w1e, cw);
    node_proj_kernel<<<(N_NODES + 255) / 256, 256, 0, stream>>>(x, w1n, cw, y);
    edge_kernel<<<EDGE_BLOCKS, EDGE_THREADS, 0, stream>>>(ea, eidx, batch, y, w1e, cw, partials);
    reduce_kernel<<<N_GRAPHS, 256, 0, stream>>>(partials, out);
}